// Round 15
// baseline (64.387 us; speedup 1.0000x reference)
//
#include <hip/hip_runtime.h>
#include <hip/hip_bf16.h>

typedef __attribute__((ext_vector_type(8))) short bf16x8;
typedef __attribute__((ext_vector_type(4))) float f32x4;

#define NPIX 4096
#define NC   128
#define RS128 0.08838834764831845f   // 1/sqrt(128)
#define KSP  6

// global -> LDS direct DMA, 16B per lane (linear dest = wave-uniform base + lane*16)
#define GL2LDS(g, l) __builtin_amdgcn_global_load_lds( \
    (const __attribute__((address_space(1))) void*)(g), \
    (__attribute__((address_space(3))) void*)(l), 16, 0, 0)

// ---------------- prep (fused scan + copy + pack), 1024 thr — r8 verbatim ----------------
__global__ __launch_bounds__(1024) void sffa_prep(
    const float* __restrict__ x, const float* __restrict__ mask,
    ushort* __restrict__ KnW, ushort* __restrict__ QW, ushort* __restrict__ VtW,
    float* __restrict__ s0c, int* __restrict__ pixQ, int* __restrict__ cnts,
    float* __restrict__ out)
{
    __shared__ float xs[128][69];
    __shared__ float ms[64];
    __shared__ float rinv[64];
    __shared__ float ssum[64];
    __shared__ float2 part[16][64];
    __shared__ int se[64];
    __shared__ int bgn[64];
    __shared__ int tinfo[2];
    __shared__ int wredP[16], wredT[16];
    const int tid = threadIdx.x;
    const int b = blockIdx.x >> 6, nblk = blockIdx.x & 63;
    const int n0 = nblk * 64;
    const float* xb = x + (size_t)b * NC * NPIX;
    float* ob = out + (size_t)b * NC * NPIX;

    #pragma unroll
    for (int it = 0; it < 2; ++it) {
        int e4 = it * 1024 + tid;
        int c = e4 >> 4, n4 = (e4 & 15) * 4;
        float4 v = *(const float4*)(xb + (size_t)c * NPIX + n0 + n4);
        xs[c][n4+0] = v.x; xs[c][n4+1] = v.y; xs[c][n4+2] = v.z; xs[c][n4+3] = v.w;
        *(float4*)(ob + (size_t)c * NPIX + n0 + n4) = v;
    }
    if (tid < 16) {
        float4 mv = *(const float4*)(mask + (size_t)b * NPIX + n0 + tid * 4);
        ms[tid*4+0] = mv.x; ms[tid*4+1] = mv.y; ms[tid*4+2] = mv.z; ms[tid*4+3] = mv.w;
    }
    {
        const int lane = tid & 63, w = tid >> 6;
        float4 mv = *(const float4*)(mask + (size_t)b * NPIX + tid * 4);
        int f0 = mv.x < 0.5f ? 0x10000 : 1;
        int f1 = mv.y < 0.5f ? 0x10000 : 1;
        int f2 = mv.z < 0.5f ? 0x10000 : 1;
        int f3 = mv.w < 0.5f ? 0x10000 : 1;
        int p0 = tid * 4;
        int pre = 0, tot = f0 + f1 + f2 + f3;
        if (p0 + 0 < n0) pre += f0;
        if (p0 + 1 < n0) pre += f1;
        if (p0 + 2 < n0) pre += f2;
        if (p0 + 3 < n0) pre += f3;
        #pragma unroll
        for (int d = 1; d < 64; d <<= 1) {
            pre += __shfl_xor(pre, d);
            tot += __shfl_xor(tot, d);
        }
        if (lane == 0) { wredP[w] = pre; wredT[w] = tot; }
    }
    __syncthreads();
    if (tid < 64) {
        int vP = (tid < 16) ? wredP[tid] : 0;
        int vT = (tid < 16) ? wredT[tid] : 0;
        #pragma unroll
        for (int d = 1; d < 16; d <<= 1) {
            vP += __shfl_xor(vP, d);
            vT += __shfl_xor(vT, d);
        }
        int base  = __shfl(vP, 0);
        int total = __shfl(vT, 0);
        if (tid == 0 && nblk == 0) {
            cnts[b * 2]     = total & 0xffff;
            cnts[b * 2 + 1] = total >> 16;
        }
        int f = ms[tid] > 0.5f ? 1 : 0x10000;
        int s = f;
        #pragma unroll
        for (int d = 1; d < 64; d <<= 1) {
            int t = __shfl_up(s, d);
            if (tid >= d) s += t;
        }
        se[tid] = base + s - f;
    }
    __syncthreads();
    {
        int p = tid & 63, qd = tid >> 6;
        float m = ms[p];
        float s2 = 0.f, s1 = 0.f;
        #pragma unroll
        for (int i = 0; i < 8; ++i) {
            float xv = xs[qd*8 + i][p];
            float k = fmaf(xv, m, 1e-7f);
            s2 = fmaf(k, k, s2);
            s1 += xv;
        }
        part[qd][p] = make_float2(s2, s1);
    }
    __syncthreads();
    if (tid < 64) {
        float s2 = 0.f, s1 = 0.f;
        #pragma unroll
        for (int k = 0; k < 16; ++k) { float2 t = part[k][tid]; s2 += t.x; s1 += t.y; }
        rinv[tid] = rsqrtf(s2);
        ssum[tid] = s1 * RS128;
    }
    __syncthreads();
    #pragma unroll
    for (int it = 0; it < 4; ++it) {
        int e2 = it * 1024 + tid;
        int n = e2 >> 6, cp = (e2 & 63) * 2;
        int pe = se[n];
        float x0 = xs[cp][n], x1 = xs[cp+1][n];
        if (ms[n] > 0.5f) {
            int slot = pe & 0xffff;
            float k0 = x0 + 1e-7f, k1 = x1 + 1e-7f;
            float r = rinv[n];
            __hip_bfloat162 kn;
            kn.x = __float2bfloat16(k0 * r); kn.y = __float2bfloat16(k1 * r);
            *(__hip_bfloat162*)(KnW + ((size_t)b * NPIX + slot) * NC + cp) = kn;
        } else {
            int slot = pe >> 16;
            __hip_bfloat162 q;
            q.x = __float2bfloat16(x0); q.y = __float2bfloat16(x1);
            *(__hip_bfloat162*)(QW + ((size_t)b * NPIX + slot) * NC + cp) = q;
        }
    }
    if (tid < 64) {
        if (ms[tid] < 0.5f) {
            int slot = se[tid] >> 16;
            s0c [(size_t)b * NPIX + slot] = ssum[tid];
            pixQ[(size_t)b * NPIX + slot] = n0 + tid;
        } else {
            bgn[(se[tid] & 0xffff) - (se[0] & 0xffff)] = tid;
        }
    }
    if (tid == 0) {
        tinfo[0] = se[0] & 0xffff;
        tinfo[1] = (se[63] & 0xffff) + (ms[63] > 0.5f ? 1 : 0) - (se[0] & 0xffff);
    }
    __syncthreads();
    {
        const int s0b = tinfo[0], nbg = tinfo[1];
        const int j = tid & 63, cg = tid >> 6;
        if (j < nbg) {
            int n = bgn[j];
            ushort* vcol = VtW + (size_t)b * NC * NPIX + s0b + j;
            #pragma unroll
            for (int cc = 0; cc < 8; ++cc) {
                int c = cg * 8 + cc;
                __hip_bfloat16 h = __float2bfloat16(xs[c][n] + 1e-7f);
                vcol[(size_t)c * NPIX] = *(ushort*)&h;
            }
        }
    }
}

// ---------------- attn: 64q, 64k tiles, KS=6, SINGLE buffer -> 3 blocks/CU ----------
#define L_V   16384
#define L_P   32768      // 8 waves * 1280 = 10240
#define L_ML  43008      // 4 * 64 floats
#define L_SZ  44032

__global__ __launch_bounds__(512, 6) void sffa_attn(
    const ushort* __restrict__ KnW, const ushort* __restrict__ QW,
    const ushort* __restrict__ VtW, const int* __restrict__ cnts,
    ushort* __restrict__ partW, float* __restrict__ mlW)
{
    __shared__ __align__(16) char smem[L_SZ];
    const int tid  = threadIdx.x;
    const int w = tid >> 6, lane = tid & 63;
    const int l15 = lane & 15, g = lane >> 4;
    const int bx = (int)blockIdx.x;
    const int per = 64 * KSP;
    const int b = bx / per;
    const int rem = bx - b * per;
    const int qblk = rem / KSP, ks = rem - (rem / KSP) * KSP;
    const int q0 = qblk * 64;
    const int cntK = cnts[b * 2], cntQ = cnts[b * 2 + 1];
    if (q0 >= cntQ) return;
    const int blk = (b * 64 + qblk) * KSP + ks;

    const int nk64 = (cntK + 63) >> 6;
    const int tpk  = (nk64 + KSP - 1) / KSP;
    const int t0   = ks * tpk;
    const int NTK  = min(t0 + tpk, nk64) - t0;

    if (NTK <= 0) {
        unsigned* pz = (unsigned*)(partW + (size_t)blk * 8192);
        #pragma unroll
        for (int i = 0; i < 8; ++i) pz[i * 512 + tid] = 0u;
        if (tid < 64)
            *(float2*)(mlW + ((size_t)blk * 64 + tid) * 2) = make_float2(-1e30f, 0.f);
        return;
    }

    const int half = w >> 2;
    const int wq   = w & 3;
    const int kbase = t0 * 64;

    const ushort* Knb = KnW + (size_t)b * NPIX * NC;
    const ushort* Vtb = VtW + (size_t)b * NC * NPIX;

    // Q fragments direct from global (L2-hot, once per block)
    bf16x8 qf[4];
    {
        const ushort* Qrow = QW + ((size_t)b * NPIX + q0 + wq * 16 + l15) * NC;
        #pragma unroll
        for (int kc = 0; kc < 4; ++kc)
            qf[kc] = *(const bf16x8*)(Qrow + 32 * kc + 8 * g);
    }

    // pre-swizzled GLOBAL sources (inverse-swz source + linear LDS dest)
    const int rK = tid >> 4;
    const char* srcK = (const char*)(Knb + (size_t)(kbase + rK) * NC)
                     + (((tid & 15) ^ (rK & 15)) << 4);
    const int rV = tid >> 3;
    const char* srcV = (const char*)(Vtb + (size_t)rV * NPIX + kbase)
                     + (((tid & 7) ^ (rV & 7)) << 4);
    char* d0 = smem + tid * 16;

    // stage tile 0
    GL2LDS(srcK,        d0);
    GL2LDS(srcK + 8192, d0 + 8192);
    GL2LDS(srcV,                           d0 + 16384);
    GL2LDS(srcV + (size_t)64 * NPIX * 2,   d0 + 24576);
    __syncthreads();

    f32x4 acc[8];
    const f32x4 fzero = {0.f, 0.f, 0.f, 0.f};
    #pragma unroll
    for (int i = 0; i < 8; ++i) acc[i] = fzero;
    float mrun = -1e30f, lrun = 0.f;
    char* Pw = smem + L_P + w * 1280;

    for (int kt = 0; kt < NTK; ++kt) {
        f32x4 sa0 = fzero, sa1 = fzero;
        {
            const char* rb0 = smem + (half * 32 + l15) * 256;
            const char* rb1 = rb0 + 4096;
            const int sw = l15 << 4;
            __builtin_amdgcn_s_setprio(1);
            #pragma unroll
            for (int kc = 0; kc < 4; ++kc) {
                int off = (64 * kc + 16 * g) ^ sw;
                bf16x8 a0 = *(const bf16x8*)(rb0 + off);
                bf16x8 a1 = *(const bf16x8*)(rb1 + off);
                sa0 = __builtin_amdgcn_mfma_f32_16x16x32_bf16(a0, qf[kc], sa0, 0, 0, 0);
                sa1 = __builtin_amdgcn_mfma_f32_16x16x32_bf16(a1, qf[kc], sa1, 0, 0, 0);
            }
            __builtin_amdgcn_s_setprio(0);
        }
        {
            int kg0 = (t0 + kt) * 64;
            if (kg0 + 64 > cntK) {
                int kb = cntK - kg0;
                int kr = half * 32 + 4 * g;
                #pragma unroll
                for (int r = 0; r < 4; ++r) {
                    if (kr + r >= kb)      sa0[r] = -3e38f;
                    if (kr + 16 + r >= kb) sa1[r] = -3e38f;
                }
            }
        }
        float tmax = fmaxf(fmaxf(fmaxf(sa0[0], sa0[1]), fmaxf(sa0[2], sa0[3])),
                           fmaxf(fmaxf(sa1[0], sa1[1]), fmaxf(sa1[2], sa1[3])));
        tmax = fmaxf(tmax, __shfl_xor(tmax, 16));
        tmax = fmaxf(tmax, __shfl_xor(tmax, 32));
        bool grow = !__all(tmax <= mrun + 8.f);
        float mnew = grow ? fmaxf(mrun, tmax) : mrun;
        float p0[4], p1[4];
        float ts = 0.f;
        #pragma unroll
        for (int r = 0; r < 4; ++r) { p0[r] = __expf(sa0[r] - mnew); ts += p0[r]; }
        #pragma unroll
        for (int r = 0; r < 4; ++r) { p1[r] = __expf(sa1[r] - mnew); ts += p1[r]; }
        ts += __shfl_xor(ts, 16);
        ts += __shfl_xor(ts, 32);
        if (grow) {
            float sc = __expf(mrun - mnew);
            lrun = lrun * sc + ts;
            float scr[4];
            #pragma unroll
            for (int r = 0; r < 4; ++r) scr[r] = __shfl(sc, 4 * g + r);
            #pragma unroll
            for (int ct = 0; ct < 8; ++ct) {
                acc[ct][0] *= scr[0]; acc[ct][1] *= scr[1];
                acc[ct][2] *= scr[2]; acc[ct][3] *= scr[3];
            }
            mrun = mnew;
        } else {
            lrun += ts;
        }
        union { __hip_bfloat162 h; unsigned u; } ua0, ua1, ub0, ub1;
        ua0.h.x = __float2bfloat16(p0[0]); ua0.h.y = __float2bfloat16(p0[1]);
        ua1.h.x = __float2bfloat16(p0[2]); ua1.h.y = __float2bfloat16(p0[3]);
        ub0.h.x = __float2bfloat16(p1[0]); ub0.h.y = __float2bfloat16(p1[1]);
        ub1.h.x = __float2bfloat16(p1[2]); ub1.h.y = __float2bfloat16(p1[3]);
        *(int2*)(Pw + l15 * 80 +      8 * g) = make_int2((int)ua0.u, (int)ua1.u);
        *(int2*)(Pw + l15 * 80 + 32 + 8 * g) = make_int2((int)ub0.u, (int)ub1.u);
        bf16x8 pf = *(const bf16x8*)(Pw + l15 * 80 + 16 * g);
        {
            const char* vb = smem + L_V;
            __builtin_amdgcn_s_setprio(1);
            #pragma unroll
            for (int ct = 0; ct < 8; ++ct) {
                int c = 16 * ct + l15;
                bf16x8 vf = *(const bf16x8*)(vb + c * 128 +
                                             ((64 * half + 16 * g) ^ ((c & 7) << 4)));
                acc[ct] = __builtin_amdgcn_mfma_f32_16x16x32_bf16(pf, vf, acc[ct], 0, 0, 0);
            }
            __builtin_amdgcn_s_setprio(0);
        }
        __syncthreads();                       // all waves done reading this tile
        if (kt + 1 < NTK) {
            const char* sK = srcK + (size_t)(kt + 1) * 16384;
            const char* sV = srcV + (size_t)(kt + 1) * 128;
            GL2LDS(sK,        d0);
            GL2LDS(sK + 8192, d0 + 8192);
            GL2LDS(sV,                         d0 + 16384);
            GL2LDS(sV + (size_t)64 * NPIX * 2, d0 + 24576);
            __syncthreads();                   // drains DMA (compiler vmcnt(0))
        }
    }

    // ---- merge key-half partials; write unnormalized partial + (m,l) ----
    float* ma = (float*)(smem + L_ML);
    float* la = ma + 64; float* mb = la + 64; float* lb = mb + 64;
    const int q = wq * 16 + l15;
    if (g == 0) {
        if (half == 0) { ma[q] = mrun; la[q] = lrun; }
        else           { mb[q] = mrun; lb[q] = lrun; }
    }
    __syncthreads();
    float* agg = (float*)smem;   // [128][68] fp32 = 34816 B, spans K+V+P region
    {
        float mstar = fmaxf(ma[q], mb[q]);
        float f = __expf(mrun - mstar);
        float fr[4];
        #pragma unroll
        for (int r = 0; r < 4; ++r) fr[r] = __shfl(f, 4 * g + r);
        if (half == 1) {
            #pragma unroll
            for (int ct = 0; ct < 8; ++ct) {
                int c = 16 * ct + l15;
                #pragma unroll
                for (int r = 0; r < 4; ++r)
                    agg[c * 68 + wq * 16 + 4 * g + r] = acc[ct][r] * fr[r];
            }
        }
        __syncthreads();
        if (half == 0) {
            #pragma unroll
            for (int ct = 0; ct < 8; ++ct) {
                int c = 16 * ct + l15;
                #pragma unroll
                for (int r = 0; r < 4; ++r) {
                    int idx = c * 68 + wq * 16 + 4 * g + r;
                    agg[idx] = acc[ct][r] * fr[r] + agg[idx];
                }
            }
        }
    }
    __syncthreads();
    if (tid < 64) {
        float M = fmaxf(ma[tid], mb[tid]);
        float ls = la[tid] * __expf(ma[tid] - M) + lb[tid] * __expf(mb[tid] - M);
        *(float2*)(mlW + ((size_t)blk * 64 + tid) * 2) = make_float2(M, ls);
    }
    ushort* pdst = partW + (size_t)blk * 8192;
    #pragma unroll
    for (int it = 0; it < 8; ++it) {
        int idx = it * 512 + tid;
        int c = idx >> 5, n2 = (idx & 31) * 2;
        __hip_bfloat162 h;
        h.x = __float2bfloat16(agg[c * 68 + n2]);
        h.y = __float2bfloat16(agg[c * 68 + n2 + 1]);
        *(__hip_bfloat162*)(pdst + c * 64 + n2) = h;
    }
}

// ---------------- comb: slot-space combine + scatter (KS=6) ----------------
__global__ __launch_bounds__(256) void sffa_comb(
    const ushort* __restrict__ partW, const float* __restrict__ mlW,
    const float* __restrict__ s0c, const int* __restrict__ pixQ,
    const int* __restrict__ cnts, float* __restrict__ out)
{
    __shared__ float wgtL[KSP][64];
    __shared__ int pixnL[64];
    const int tid = threadIdx.x;
    const int bx = blockIdx.x;
    const int b = bx >> 7, qb = (bx >> 1) & 63, ch = bx & 1;
    const int cntK = cnts[b * 2], cntQ = cnts[b * 2 + 1];
    if (qb * 64 >= cntQ) return;
    const int blkbase = (b * 64 + qb) * KSP;
    const float m0f = (float)(NPIX - cntK);

    if (tid < 64) {
        int slot = qb * 64 + tid;
        int pix = -1;
        if (slot < cntQ) {
            pix = pixQ[(size_t)b * NPIX + slot];
            float s0 = s0c[(size_t)b * NPIX + slot];
            float M = s0;
            float2 mls[KSP];
            #pragma unroll
            for (int k = 0; k < KSP; ++k) {
                mls[k] = *(const float2*)(mlW + ((size_t)(blkbase + k) * 64 + tid) * 2);
                M = fmaxf(M, mls[k].x);
            }
            float L = m0f * __expf(s0 - M);
            #pragma unroll
            for (int k = 0; k < KSP; ++k) L += mls[k].y * __expf(mls[k].x - M);
            float Li = 1.f / L;
            #pragma unroll
            for (int k = 0; k < KSP; ++k)
                wgtL[k][tid] = __expf(mls[k].x - M) * Li;
        }
        pixnL[tid] = pix;
    }
    __syncthreads();

    float* ob = out + ((size_t)b * NC + ch * 64) * NPIX;
    const ushort* pb = partW + (size_t)blkbase * 8192 + ch * 4096;
    #pragma unroll
    for (int it = 0; it < 2; ++it) {
        int idx = it * 256 + tid;
        int c = idx >> 3, grp = idx & 7;
        float v[8] = {0.f,0.f,0.f,0.f,0.f,0.f,0.f,0.f};
        #pragma unroll
        for (int k = 0; k < KSP; ++k) {
            ushort u[8];
            *(int4*)u = *(const int4*)(pb + (size_t)k * 8192 + c * 64 + grp * 8);
            #pragma unroll
            for (int j = 0; j < 8; ++j)
                v[j] = fmaf(__uint_as_float((unsigned)u[j] << 16),
                            wgtL[k][grp * 8 + j], v[j]);
        }
        #pragma unroll
        for (int j = 0; j < 8; ++j) {
            int pix = pixnL[grp * 8 + j];
            if (pix >= 0) ob[(size_t)c * NPIX + pix] = v[j];
        }
    }
}

extern "C" void kernel_launch(void* const* d_in, const int* in_sizes, int n_in,
                              void* d_out, int out_size, void* d_ws, size_t ws_size,
                              hipStream_t stream) {
    const float* x    = (const float*)d_in[0];
    const float* mask = (const float*)d_in[1];
    char* ws = (char*)d_ws;
    const size_t MBy = 1024 * 1024;
    const size_t KBy = 1024;

    ushort* KnW = (ushort*)(ws);                      // 4 MB compact Kn
    ushort* QW  = (ushort*)(ws + 4 * MBy);            // 4 MB compact Q
    ushort* VtW = (ushort*)(ws + 8 * MBy);            // 4 MB compact V^T

    ushort* partW = (ushort*)(ws + 12 * MBy);         // 1536 blks * 16 KB = 24 MB... (KSP*4MB=24/4*6=...)
    char* tail = ws + 12 * MBy + (size_t)(4 * 64 * KSP) * 16 * KBy;   // 12MB + 24MB
    float* mlW  = (float*)(tail);                      // 1536 * 512 B = 768 KB
    float* s0c  = (float*)(tail + 1024 * KBy);         // 64 KB
    int*   pixQ = (int*)(tail + 1088 * KBy);           // 64 KB
    int*   cnts = (int*)(tail + 1152 * KBy);           // 32 B

    sffa_prep <<<256, 1024, 0, stream>>>(x, mask, KnW, QW, VtW, s0c, pixQ, cnts,
                                         (float*)d_out);
    sffa_attn <<<4 * 64 * KSP, 512, 0, stream>>>(KnW, QW, VtW, cnts, partW, mlW);
    sffa_comb <<<4 * 128, 256, 0, stream>>>(partW, mlW, s0c, pixQ, cnts,
                                            (float*)d_out);
}